// Round 5
// baseline (193.461 us; speedup 1.0000x reference)
//
#include <hip/hip_runtime.h>
#include <hip/hip_bf16.h>
#include <stdint.h>

#define NB 4
#define NS 2048
#define ND 1024
#define NH 16
#define NDH 64
#define NM (NB*NS)   // 8192 rows

typedef __attribute__((ext_vector_type(8))) short bf16x8;
typedef __attribute__((ext_vector_type(4))) float f32x4;
typedef __attribute__((ext_vector_type(16))) float f32x16;
typedef __attribute__((ext_vector_type(8))) unsigned short u16x8;

static __device__ __forceinline__ unsigned short f2bf(float f) {
  union { float f; unsigned u; } v; v.f = f;
  return (unsigned short)((v.u + 0x7FFFu + ((v.u >> 16) & 1u)) >> 16);
}

static __device__ __forceinline__ void gload_lds16(const void* g, void* l) {
  __builtin_amdgcn_global_load_lds(
      (__attribute__((address_space(1))) unsigned int*)(uintptr_t)g,
      (__attribute__((address_space(3))) unsigned int*)(uintptr_t)(size_t)(l),
      16, 0, 0);
}

static __device__ __forceinline__ unsigned cvtpk(float lo, float hi) {
  unsigned r;
  asm("v_cvt_pk_bf16_f32 %0, %1, %2" : "=v"(r) : "v"(lo), "v"(hi));
  return r;
}
static __device__ __forceinline__ void plswap(unsigned &a, unsigned &b) {
  asm("v_permlane32_swap_b32 %0, %1" : "+v"(a), "+v"(b));
}

// ---------------- fp32 -> bf16 convert: x (large) ---------------------------
__global__ void k_cvt(const float* __restrict__ src, unsigned short* __restrict__ dst, int n8) {
  int i = blockIdx.x * blockDim.x + threadIdx.x;
  if (i >= n8) return;
  const float4* s = (const float4*)src + (size_t)i * 2;
  float4 a = s[0], b = s[1];
  u16x8 o;
  o[0]=f2bf(a.x); o[1]=f2bf(a.y); o[2]=f2bf(a.z); o[3]=f2bf(a.w);
  o[4]=f2bf(b.x); o[5]=f2bf(b.y); o[6]=f2bf(b.z); o[7]=f2bf(b.w);
  *((u16x8*)dst + i) = o;
}

// ---------------- fused 4-weight convert ------------------------------------
__global__ void k_cvtw(const float* __restrict__ s0, const float* __restrict__ s1,
                       const float* __restrict__ s2, const float* __restrict__ s3,
                       unsigned short* __restrict__ d0, unsigned short* __restrict__ d1,
                       unsigned short* __restrict__ d2, unsigned short* __restrict__ d3) {
  constexpr int NG = ND*ND/8;  // groups per matrix
  int i = blockIdx.x * blockDim.x + threadIdx.x;
  const int m = i / NG, j = i - m*NG;
  const float* src = m==0 ? s0 : (m==1 ? s1 : (m==2 ? s2 : s3));
  unsigned short* dst = m==0 ? d0 : (m==1 ? d1 : (m==2 ? d2 : d3));
  const float4* s = (const float4*)src + (size_t)j * 2;
  float4 a = s[0], b = s[1];
  u16x8 o;
  o[0]=f2bf(a.x); o[1]=f2bf(a.y); o[2]=f2bf(a.z); o[3]=f2bf(a.w);
  o[4]=f2bf(b.x); o[5]=f2bf(b.y); o[6]=f2bf(b.z); o[7]=f2bf(b.w);
  *((u16x8*)dst + j) = o;
}

// ---------------- fused QKV GEMM, 256x256 tile, counted-vmcnt pipeline ------
// grid (12, 32), 512 threads (8 waves, 2M x 4N). BK=32, NT=32 K-tiles.
// Per tile: 4 phases, each {ds_read quadrant; stage 1 chunk; [vmcnt]; barrier;
// lgkmcnt(0); 8 MFMA}. Stage schedule: P1:B1(u+1) P2:A0(u+1) P3:A1(u+1)
// P4:B0(u+2)+vmcnt(1). Every staged region is >=2 barrier-phases past its
// last ds_read; vmcnt(1) at P4 guarantees next tile resident at its P1.
__global__ __launch_bounds__(512, 2)
void k_gemm_qkv8(const unsigned short* __restrict__ A,
                 const unsigned short* __restrict__ Wqp, const unsigned short* __restrict__ Wkp,
                 const unsigned short* __restrict__ Wvp,
                 const float* __restrict__ bqp, const float* __restrict__ bkp,
                 const float* __restrict__ bvp,
                 unsigned short* __restrict__ Qo, unsigned short* __restrict__ Ko,
                 unsigned short* __restrict__ Vto, float qscale)
{
  constexpr int K = ND, BK = 32, NT = K / BK;   // 32 tiles
  __shared__ unsigned short Al[2][256*BK];      // 16 KB each buf
  __shared__ unsigned short Bl[2][256*BK];
  const int tid = threadIdx.x;
  const int lane = tid & 63, wid = tid >> 6;
  const int g = lane >> 4, lr = lane & 15;
  const int wr = wid >> 2, wc = wid & 3;        // 2 x 4 waves
  const int bc = blockIdx.x, br = blockIdx.y;
  const int mat = bc >> 2;
  const unsigned short* W = mat==0 ? Wqp : (mat==1 ? Wkp : Wvp);
  const float* bias = mat==0 ? bqp : (mat==1 ? bkp : bvp);
  const float scale = mat==0 ? qscale : 1.0f;

  const unsigned short* Ab = A + (size_t)br*256*K;
  const unsigned short* Wb = W + (size_t)(bc & 3)*256*K;

  f32x4 acc[8][4];
  #pragma unroll
  for (int m=0;m<8;m++)
    #pragma unroll
    for (int n=0;n<4;n++) acc[m][n] = f32x4{0.f,0.f,0.f,0.f};

  // staging map: chunk = 128 rows x 32 cols (8 KB) = 1 gload_lds per thread
  const int st_r = tid >> 2;            // 0..127 row within chunk
  const int st_c = (tid & 3) * 8;       // element col
  auto stageA = [&](int buf, int half, int t) {
    const int tc = t < NT ? t : NT-1;
    gload_lds16(Ab + (size_t)(half*128 + st_r)*K + tc*BK + st_c,
                &Al[buf][half*4096 + tid*8]);
  };
  auto stageB = [&](int buf, int half, int t) {
    const int tc = t < NT ? t : NT-1;
    gload_lds16(Wb + (size_t)(half*128 + st_r)*K + tc*BK + st_c,
                &Bl[buf][half*4096 + tid*8]);
  };

#define QKV_PHASE(P, STAGE, VM) do {                                           \
    bf16x8 af0 = *(const bf16x8*)&Al[cur][(wr*128 + (P)*32 +  0 + lr)*BK + g*8]; \
    bf16x8 af1 = *(const bf16x8*)&Al[cur][(wr*128 + (P)*32 + 16 + lr)*BK + g*8]; \
    STAGE;                                                                     \
    VM;                                                                        \
    __builtin_amdgcn_s_barrier();                                              \
    asm volatile("s_waitcnt lgkmcnt(0)" ::: "memory");                         \
    __builtin_amdgcn_sched_barrier(0);                                         \
    __builtin_amdgcn_s_setprio(1);                                             \
    _Pragma("unroll")                                                          \
    for (int n=0;n<4;n++) {                                                    \
      acc[(P)*2+0][n] = __builtin_amdgcn_mfma_f32_16x16x32_bf16(af0, bfr[n], acc[(P)*2+0][n],0,0,0); \
      acc[(P)*2+1][n] = __builtin_amdgcn_mfma_f32_16x16x32_bf16(af1, bfr[n], acc[(P)*2+1][n],0,0,0); \
    }                                                                          \
    __builtin_amdgcn_s_setprio(0);                                             \
  } while(0)

#define QKV_VMW do { asm volatile("s_waitcnt vmcnt(1)" ::: "memory");          \
                     __builtin_amdgcn_sched_barrier(0); } while(0)

  // prologue: tile0 fully + B0(1); leave B0(1) outstanding
  stageB(0, 0, 0); stageB(0, 1, 0); stageA(0, 0, 0); stageA(0, 1, 0);
  stageB(1, 0, 1);
  QKV_VMW;
  __builtin_amdgcn_s_barrier();

  for (int u = 0; u < NT; ++u) {
    const int cur = u & 1;
    bf16x8 bfr[4];
    #pragma unroll
    for (int n=0;n<4;n++)
      bfr[n] = *(const bf16x8*)&Bl[cur][(wc*64 + n*16 + lr)*BK + g*8];
    QKV_PHASE(0, stageB(cur^1, 1, u+1), );        // B1(u+1)
    QKV_PHASE(1, stageA(cur^1, 0, u+1), );        // A0(u+1)
    QKV_PHASE(2, stageA(cur^1, 1, u+1), );        // A1(u+1)
    QKV_PHASE(3, stageB(cur,   0, u+2), QKV_VMW); // B0(u+2), counted wait
    __builtin_amdgcn_s_barrier();                 // close tile: joins readers
  }
#undef QKV_PHASE
#undef QKV_VMW

  // epilogue
  #pragma unroll
  for (int m=0;m<8;m++) {
    const int rbase = br*256 + wr*128 + m*16 + g*4;
    #pragma unroll
    for (int n=0;n<4;n++) {
      const int colm = (bc & 3)*256 + wc*64 + n*16 + lr;   // col within matrix
      const float bv = bias[colm];
      const int h = colm >> 6, dh = colm & 63;
      #pragma unroll
      for (int j=0;j<4;j++) {
        const int row = rbase + j;
        const float val = (acc[m][n][j] + bv) * scale;
        const int b = row >> 11, s = row & (NS-1);
        if (mat == 2)
          Vto[(((size_t)b*NH + h)*NDH + dh)*NS + s] = f2bf(val);
        else
          (mat==0 ? Qo : Ko)[(((size_t)b*NH + h)*NS + s)*NDH + dh] = f2bf(val);
      }
    }
  }
}

// ---------------- O-projection GEMM (fp32 out), 2-phase dbuf ----------------
__global__ __launch_bounds__(256)
void k_gemm_o(const unsigned short* __restrict__ A,
              const unsigned short* __restrict__ W,
              const float* __restrict__ bias,
              float* __restrict__ outp)
{
  constexpr int K = ND, BK = 32;
  __shared__ unsigned short Alds[2][128*BK];
  __shared__ unsigned short Blds[2][128*BK];
  const int tid = threadIdx.x;
  const int wid = tid >> 6, lane = tid & 63;
  const int g = lane >> 4, lr = lane & 15;
  const int bc = blockIdx.x, br = blockIdx.y;
  const int wr = (wid >> 1) << 6, wc = (wid & 1) << 6;

  f32x4 acc[4][4];
  #pragma unroll
  for (int m=0;m<4;m++)
    #pragma unroll
    for (int n=0;n<4;n++) acc[m][n] = f32x4{0.f,0.f,0.f,0.f};

  const unsigned short* Ab = A + (size_t)br*128*K;
  const unsigned short* Wb = W + (size_t)bc*128*K;
  const int r0 = tid >> 2, c0 = (tid & 3) * 8;
  const int r1 = (256 + tid) >> 2;

  auto stage = [&](int b, int k0) {
    gload_lds16(Ab + (size_t)r0*K + k0 + c0, &Alds[b][tid*8]);
    gload_lds16(Ab + (size_t)r1*K + k0 + c0, &Alds[b][(256+tid)*8]);
    gload_lds16(Wb + (size_t)r0*K + k0 + c0, &Blds[b][tid*8]);
    gload_lds16(Wb + (size_t)r1*K + k0 + c0, &Blds[b][(256+tid)*8]);
  };

  stage(0, 0);
  __syncthreads();
  int cur = 0;
  for (int k0 = 0; k0 < K; k0 += BK) {
    if (k0 + BK < K) stage(cur ^ 1, k0 + BK);
    bf16x8 af[4], bfr[4];
    #pragma unroll
    for (int m=0;m<4;m++) af[m]  = *(const bf16x8*)&Alds[cur][(wr + m*16 + lr)*BK + g*8];
    #pragma unroll
    for (int n=0;n<4;n++) bfr[n] = *(const bf16x8*)&Blds[cur][(wc + n*16 + lr)*BK + g*8];
    __builtin_amdgcn_s_setprio(1);
    #pragma unroll
    for (int m=0;m<4;m++)
      #pragma unroll
      for (int n=0;n<4;n++)
        acc[m][n] = __builtin_amdgcn_mfma_f32_16x16x32_bf16(af[m], bfr[n], acc[m][n], 0, 0, 0);
    __builtin_amdgcn_s_setprio(0);
    __syncthreads();
    cur ^= 1;
  }

  #pragma unroll
  for (int m=0;m<4;m++) {
    const int rbase = br*128 + wr + m*16 + g*4;
    #pragma unroll
    for (int n=0;n<4;n++) {
      const int col = bc*128 + wc + n*16 + lr;
      const float bv = bias[col];
      #pragma unroll
      for (int j=0;j<4;j++)
        outp[(size_t)(rbase + j)*ND + col] = acc[m][n][j] + bv;
    }
  }
}

// ---------------- causal flash attention, swapped-QK^T 32x32 MFMA -----------
// grid (B*H, S/64); 2 waves x 32 q-rows; KV tiles of 64 keys, 2-phase dbuf.
// Q pre-scaled by 0.125*log2e. Fixed-max softmax: P = 2^st, normalize at end.
__global__ __launch_bounds__(128, 4)
void k_attn(const unsigned short* __restrict__ Qg,   // [BH][S][64]
            const unsigned short* __restrict__ Kg,   // [BH][S][64]
            const unsigned short* __restrict__ Vtg,  // [BH][64][S]  (V^T)
            unsigned short* __restrict__ Og)         // [B][S][H*64] bf16
{
  __shared__ unsigned short Klds[2][64*64];  // [64 keys][64 dh], 16B-slot XOR swz
  __shared__ unsigned short Vlds[2][64*64];  // [64 dh][64 keys], 16B-slot XOR swz
  __shared__ float scL[64];
  const int tid = threadIdx.x;
  const int wid = tid >> 6, lane = tid & 63;
  const int ql = lane & 31, hi = lane >> 5;
  const int bh = blockIdx.x;
  const int qt = (int)gridDim.y - 1 - (int)blockIdx.y;  // longest first
  const int qbB = qt * 64;
  const int wq = qbB + wid * 32;

  const unsigned short* Qh  = Qg  + (size_t)bh*NS*NDH;
  const unsigned short* Kh  = Kg  + (size_t)bh*NS*NDH;
  const unsigned short* Vth = Vtg + (size_t)bh*NDH*NS;

  // Q fragments (B-operand): lane holds Q[q = wq+ql][dh = ds*16 + hi*8 + e]
  bf16x8 qf[4];
  #pragma unroll
  for (int ds=0; ds<4; ++ds)
    qf[ds] = *(const bf16x8*)(Qh + (size_t)(wq+ql)*NDH + ds*16 + hi*8);

  f32x16 acc0, acc1;
  #pragma unroll
  for (int r=0;r<16;++r) { acc0[r]=0.f; acc1[r]=0.f; }
  float lsum = 0.f;

  const int sr = tid >> 3, sc = tid & 7;
  const int swz = (sc ^ (sr & 7)) * 8;   // constant per lane

  auto stageKV = [&](int b, int kbase) {
    #pragma unroll
    for (int c=0;c<4;c++)
      gload_lds16(Kh + (size_t)(kbase + c*16 + sr)*NDH + swz, &Klds[b][(c*128+tid)*8]);
    #pragma unroll
    for (int c=0;c<4;c++)
      gload_lds16(Vth + (size_t)(c*16 + sr)*NS + kbase + swz, &Vlds[b][(c*128+tid)*8]);
  };

  const int ntiles = qt + 1;
  stageKV(0, 0);
  __syncthreads();
  int cur = 0;
  for (int kt = 0; kt < ntiles; ++kt) {
    const int kbase = kt << 6;
    if (kt + 1 < ntiles) stageKV(cur ^ 1, (kt+1) << 6);   // prefetch next KV tile
    #pragma unroll
    for (int h32 = 0; h32 < 2; ++h32) {
      const int kb32 = kbase + h32*32;
      if (kb32 <= wq) {   // wave-uniform skip of fully-masked subtiles
        // S^T[key][q] = K · Q^T
        const int krow = h32*32 + ql;
        f32x16 st;
        #pragma unroll
        for (int r=0;r<16;++r) st[r] = 0.f;
        __builtin_amdgcn_s_setprio(1);
        #pragma unroll
        for (int ds=0; ds<4; ++ds) {
          bf16x8 kf = *(const bf16x8*)&Klds[cur][krow*64 + (((ds*2+hi) ^ (krow&7))*8)];
          st = __builtin_amdgcn_mfma_f32_32x32x16_bf16(kf, qf[ds], st, 0,0,0);
        }
        __builtin_amdgcn_s_setprio(0);
        if (kb32 == wq) {  // diagonal subtile: causal mask
          #pragma unroll
          for (int r=0;r<16;++r) {
            const int koff = (r&3) + 8*(r>>2) + 4*hi;
            if (koff > ql) st[r] = -1e30f;
          }
        }
        // fixed-max softmax: P = 2^st (scores bounded, fp32 has headroom)
        float p[16]; float ls = 0.f;
        #pragma unroll
        for (int r=0;r<16;++r) { p[r] = __builtin_amdgcn_exp2f(st[r]); ls += p[r]; }
        lsum += ls;
        // pack P to PV A-fragments: cvt_pk + permlane32_swap (T12)
        unsigned w0 = cvtpk(p[0],p[1]),  w1 = cvtpk(p[2],p[3]);
        unsigned w2 = cvtpk(p[4],p[5]),  w3 = cvtpk(p[6],p[7]);
        plswap(w0, w2); plswap(w1, w3);
        unsigned z0 = cvtpk(p[8],p[9]),  z1 = cvtpk(p[10],p[11]);
        unsigned z2 = cvtpk(p[12],p[13]),z3 = cvtpk(p[14],p[15]);
        plswap(z0, z2); plswap(z1, z3);
        union { unsigned u[4]; bf16x8 v; } pk0, pk1;
        pk0.u[0]=w0; pk0.u[1]=w1; pk0.u[2]=w2; pk0.u[3]=w3;
        pk1.u[0]=z0; pk1.u[1]=z1; pk1.u[2]=z2; pk1.u[3]=z3;
        // PV: A = P (rows=queries), B = V^T-frag (cols=d)
        __builtin_amdgcn_s_setprio(1);
        #pragma unroll
        for (int nt=0; nt<2; ++nt) {
          const int drow = nt*32 + ql;
          #pragma unroll
          for (int ksl=0; ksl<2; ++ksl) {
            const int slot = h32*4 + ksl*2 + hi;
            bf16x8 vf = *(const bf16x8*)&Vlds[cur][drow*64 + ((slot ^ (drow&7))*8)];
            f32x16 &a = nt ? acc1 : acc0;
            a = __builtin_amdgcn_mfma_f32_32x32x16_bf16(ksl ? pk1.v : pk0.v, vf, a, 0,0,0);
          }
        }
        __builtin_amdgcn_s_setprio(0);
      }
    }
    __syncthreads();   // drains prefetch + joins readers of buf[cur]
    cur ^= 1;
  }

  // epilogue: l = full row sum; broadcast 1/l via LDS (per-wave region)
  const float l = lsum + __shfl_xor(lsum, 32, 64);
  scL[wid*32 + ql] = 1.0f / l;
  const int b = bh >> 4, h = bh & 15;
  #pragma unroll
  for (int rq=0; rq<4; ++rq) {
    f32x4 lv = *(const f32x4*)&scL[wid*32 + rq*8 + 4*hi];
    #pragma unroll
    for (int j=0;j<4;j++) {
      const float inv = lv[j];
      const int s = wq + rq*8 + 4*hi + j;
      unsigned short* orow = Og + ((size_t)b*NS + s)*ND + h*NDH;
      orow[ql]      = f2bf(acc0[rq*4+j] * inv);
      orow[32 + ql] = f2bf(acc1[rq*4+j] * inv);
    }
  }
}

extern "C" void kernel_launch(void* const* d_in, const int* in_sizes, int n_in,
                              void* d_out, int out_size, void* d_ws, size_t ws_size,
                              hipStream_t stream) {
  (void)in_sizes; (void)n_in; (void)out_size; (void)ws_size;
  const float* x  = (const float*)d_in[0];
  const float* Wq = (const float*)d_in[1];
  const float* bq = (const float*)d_in[2];
  const float* Wk = (const float*)d_in[3];
  const float* bk = (const float*)d_in[4];
  const float* Wv = (const float*)d_in[5];
  const float* bv = (const float*)d_in[6];
  const float* Wo = (const float*)d_in[7];
  const float* bo = (const float*)d_in[8];

  char* ws = (char*)d_ws;
  unsigned short* xb  = (unsigned short*)(ws + 0);          // 16 MiB
  unsigned short* Wqb = (unsigned short*)(ws + 16777216);   // 2 MiB
  unsigned short* Wkb = (unsigned short*)(ws + 18874368);
  unsigned short* Wvb = (unsigned short*)(ws + 20971520);
  unsigned short* Wob = (unsigned short*)(ws + 23068672);
  unsigned short* Qb  = (unsigned short*)(ws + 25165824);   // 16 MiB each
  unsigned short* Kb  = (unsigned short*)(ws + 41943040);
  unsigned short* Vtb = (unsigned short*)(ws + 58720256);   // V^T [B,H,Dh,S]
  unsigned short* Ob  = (unsigned short*)(ws + 75497472);   // end: 92274688

  k_cvt<<<dim3(NM*ND/8/256), dim3(256), 0, stream>>>(x, xb, NM*ND/8);
  k_cvtw<<<dim3(4*ND*ND/8/256), dim3(256), 0, stream>>>(Wq, Wk, Wv, Wo, Wqb, Wkb, Wvb, Wob);

  const float qscale = 0.125f * 1.4426950408889634f;  // 1/sqrt(64) * log2(e)
  k_gemm_qkv8<<<dim3(12, NM/256), dim3(512), 0, stream>>>(
      xb, Wqb, Wkb, Wvb, bq, bk, bv, Qb, Kb, Vtb, qscale);

  k_attn<<<dim3(NB*NH, NS/64), dim3(128), 0, stream>>>(Qb, Kb, Vtb, Ob);

  k_gemm_o<<<dim3(ND/128, NM/128), dim3(256), 0, stream>>>(Ob, Wob, bo, (float*)d_out);
}

// Round 6
// 179.711 us; speedup vs baseline: 1.0765x; 1.0765x over previous
//
#include <hip/hip_runtime.h>
#include <hip/hip_bf16.h>
#include <stdint.h>

#define NB 4
#define NS 2048
#define ND 1024
#define NH 16
#define NDH 64
#define NM (NB*NS)   // 8192 rows

typedef __attribute__((ext_vector_type(8))) short bf16x8;
typedef __attribute__((ext_vector_type(4))) float f32x4;
typedef __attribute__((ext_vector_type(16))) float f32x16;
typedef __attribute__((ext_vector_type(8))) unsigned short u16x8;

static __device__ __forceinline__ unsigned short f2bf(float f) {
  union { float f; unsigned u; } v; v.f = f;
  return (unsigned short)((v.u + 0x7FFFu + ((v.u >> 16) & 1u)) >> 16);
}

static __device__ __forceinline__ void gload_lds16(const void* g, void* l) {
  __builtin_amdgcn_global_load_lds(
      (__attribute__((address_space(1))) unsigned int*)(uintptr_t)g,
      (__attribute__((address_space(3))) unsigned int*)(uintptr_t)(size_t)(l),
      16, 0, 0);
}

static __device__ __forceinline__ unsigned cvtpk(float lo, float hi) {
  unsigned r;
  asm("v_cvt_pk_bf16_f32 %0, %1, %2" : "=v"(r) : "v"(lo), "v"(hi));
  return r;
}
static __device__ __forceinline__ void plswap(unsigned &a, unsigned &b) {
  asm("v_permlane32_swap_b32 %0, %1" : "+v"(a), "+v"(b));
}

// ---------------- fused fp32 -> bf16 convert: x + 4 weights, one launch -----
__global__ void k_cvt_all(const float* __restrict__ x,
                          const float* __restrict__ s0, const float* __restrict__ s1,
                          const float* __restrict__ s2, const float* __restrict__ s3,
                          unsigned short* __restrict__ xd,
                          unsigned short* __restrict__ d0, unsigned short* __restrict__ d1,
                          unsigned short* __restrict__ d2, unsigned short* __restrict__ d3) {
  constexpr int NGX = NM*ND/8;     // x groups
  constexpr int NGW = ND*ND/8;     // groups per weight matrix
  int i = blockIdx.x * blockDim.x + threadIdx.x;   // grid sized exactly
  const float* src; unsigned short* dst; int j;
  if (i < NGX) { src = x; dst = xd; j = i; }
  else {
    const int k = i - NGX, m = k / NGW;
    j = k - m*NGW;
    src = m==0 ? s0 : (m==1 ? s1 : (m==2 ? s2 : s3));
    dst = m==0 ? d0 : (m==1 ? d1 : (m==2 ? d2 : d3));
  }
  const float4* s = (const float4*)src + (size_t)j * 2;
  float4 a = s[0], b = s[1];
  u16x8 o;
  o[0]=f2bf(a.x); o[1]=f2bf(a.y); o[2]=f2bf(a.z); o[3]=f2bf(a.w);
  o[4]=f2bf(b.x); o[5]=f2bf(b.y); o[6]=f2bf(b.z); o[7]=f2bf(b.w);
  *((u16x8*)dst + j) = o;
}

// ---------------- fused QKV GEMM: grid (24, 64), 2-phase dbuf ---------------
// C[i][j] = sum_k A[i][k]*W[j][k]; mat 0/1 -> bf16 [B,H,S,Dh]; mat 2 -> V^T
__global__ __launch_bounds__(256, 4)
void k_gemm_qkv(const unsigned short* __restrict__ A,
                const unsigned short* __restrict__ Wqp, const unsigned short* __restrict__ Wkp,
                const unsigned short* __restrict__ Wvp,
                const float* __restrict__ bqp, const float* __restrict__ bkp,
                const float* __restrict__ bvp,
                unsigned short* __restrict__ Qo, unsigned short* __restrict__ Ko,
                unsigned short* __restrict__ Vto, float qscale)
{
  constexpr int K = ND, BK = 32;
  __shared__ unsigned short Alds[2][128*BK];
  __shared__ unsigned short Blds[2][128*BK];
  const int bcf = blockIdx.x;
  const int mat = bcf >> 3, bc = bcf & 7;
  const unsigned short* W = mat==0 ? Wqp : (mat==1 ? Wkp : Wvp);
  const float* bias = mat==0 ? bqp : (mat==1 ? bkp : bvp);
  const float scale = mat==0 ? qscale : 1.0f;

  const int tid = threadIdx.x;
  const int wid = tid >> 6, lane = tid & 63;
  const int g = lane >> 4, lr = lane & 15;
  const int br = blockIdx.y;
  const int wr = (wid >> 1) << 6, wc = (wid & 1) << 6;

  f32x4 acc[4][4];
  #pragma unroll
  for (int m=0;m<4;m++)
    #pragma unroll
    for (int n=0;n<4;n++) acc[m][n] = f32x4{0.f,0.f,0.f,0.f};

  const unsigned short* Ab = A + (size_t)br*128*K;
  const unsigned short* Wb = W + (size_t)bc*128*K;
  const int r0 = tid >> 2, c0 = (tid & 3) * 8;
  const int r1 = (256 + tid) >> 2;

  auto stage = [&](int b, int k0) {
    gload_lds16(Ab + (size_t)r0*K + k0 + c0, &Alds[b][tid*8]);
    gload_lds16(Ab + (size_t)r1*K + k0 + c0, &Alds[b][(256+tid)*8]);
    gload_lds16(Wb + (size_t)r0*K + k0 + c0, &Blds[b][tid*8]);
    gload_lds16(Wb + (size_t)r1*K + k0 + c0, &Blds[b][(256+tid)*8]);
  };

  stage(0, 0);
  __syncthreads();
  int cur = 0;
  for (int k0 = 0; k0 < K; k0 += BK) {
    if (k0 + BK < K) stage(cur ^ 1, k0 + BK);   // prefetch overlaps compute
    bf16x8 af[4], bfr[4];
    #pragma unroll
    for (int m=0;m<4;m++) af[m]  = *(const bf16x8*)&Alds[cur][(wr + m*16 + lr)*BK + g*8];
    #pragma unroll
    for (int n=0;n<4;n++) bfr[n] = *(const bf16x8*)&Blds[cur][(wc + n*16 + lr)*BK + g*8];
    __builtin_amdgcn_s_setprio(1);
    #pragma unroll
    for (int m=0;m<4;m++)
      #pragma unroll
      for (int n=0;n<4;n++)
        acc[m][n] = __builtin_amdgcn_mfma_f32_16x16x32_bf16(af[m], bfr[n], acc[m][n], 0, 0, 0);
    __builtin_amdgcn_s_setprio(0);
    __syncthreads();   // drains prefetch + joins readers of buf[cur]
    cur ^= 1;
  }

  #pragma unroll
  for (int m=0;m<4;m++) {
    const int rbase = br*128 + wr + m*16 + g*4;
    #pragma unroll
    for (int n=0;n<4;n++) {
      const int col = bc*128 + wc + n*16 + lr;
      const float bv = bias[col];
      #pragma unroll
      for (int j=0;j<4;j++) {
        const int row = rbase + j;
        const float val = (acc[m][n][j] + bv) * scale;
        const int b = row >> 11, s = row & (NS-1), h = col >> 6, dh = col & 63;
        if (mat == 2)
          Vto[(((size_t)b*NH + h)*NDH + dh)*NS + s] = f2bf(val);
        else
          (mat==0 ? Qo : Ko)[(((size_t)b*NH + h)*NS + s)*NDH + dh] = f2bf(val);
      }
    }
  }
}

// ---------------- O-projection GEMM (fp32 out), single-buffer (R3 best) -----
__global__ __launch_bounds__(256, 4)
void k_gemm_o(const unsigned short* __restrict__ A,
              const unsigned short* __restrict__ W,
              const float* __restrict__ bias,
              float* __restrict__ outp)
{
  constexpr int K = ND, BK = 32;
  __shared__ unsigned short Alds[128*BK];
  __shared__ unsigned short Blds[128*BK];
  const int tid = threadIdx.x;
  const int wid = tid >> 6, lane = tid & 63;
  const int g = lane >> 4, lr = lane & 15;
  const int bc = blockIdx.x, br = blockIdx.y;
  const int wr = (wid >> 1) << 6, wc = (wid & 1) << 6;

  f32x4 acc[4][4];
  #pragma unroll
  for (int m=0;m<4;m++)
    #pragma unroll
    for (int n=0;n<4;n++) acc[m][n] = f32x4{0.f,0.f,0.f,0.f};

  const unsigned short* Ab = A + (size_t)br*128*K;
  const unsigned short* Wb = W + (size_t)bc*128*K;
  const int r0 = tid >> 2, c0 = (tid & 3) * 8;
  const int r1 = (256 + tid) >> 2;

  for (int k0 = 0; k0 < K; k0 += BK) {
    gload_lds16(Ab + (size_t)r0*K + k0 + c0, &Alds[tid*8]);
    gload_lds16(Ab + (size_t)r1*K + k0 + c0, &Alds[(256+tid)*8]);
    gload_lds16(Wb + (size_t)r0*K + k0 + c0, &Blds[tid*8]);
    gload_lds16(Wb + (size_t)r1*K + k0 + c0, &Blds[(256+tid)*8]);
    __syncthreads();
    bf16x8 af[4], bfr[4];
    #pragma unroll
    for (int m=0;m<4;m++) af[m]  = *(const bf16x8*)&Alds[(wr + m*16 + lr)*BK + g*8];
    #pragma unroll
    for (int n=0;n<4;n++) bfr[n] = *(const bf16x8*)&Blds[(wc + n*16 + lr)*BK + g*8];
    #pragma unroll
    for (int m=0;m<4;m++)
      #pragma unroll
      for (int n=0;n<4;n++)
        acc[m][n] = __builtin_amdgcn_mfma_f32_16x16x32_bf16(af[m], bfr[n], acc[m][n], 0, 0, 0);
    __syncthreads();
  }

  #pragma unroll
  for (int m=0;m<4;m++) {
    const int rbase = br*128 + wr + m*16 + g*4;
    #pragma unroll
    for (int n=0;n<4;n++) {
      const int col = bc*128 + wc + n*16 + lr;
      const float bv = bias[col];
      #pragma unroll
      for (int j=0;j<4;j++)
        outp[(size_t)(rbase + j)*ND + col] = acc[m][n][j] + bv;
    }
  }
}

// ---------------- causal flash attention, swapped-QK^T 32x32 MFMA -----------
// grid (B*H, S/128); 4 waves x 32 q-rows; KV tiles of 64 keys, single-buffer.
// Q pre-scaled by 0.125*log2e. Fixed-max softmax: P = 2^st, normalize at end.
__global__ __launch_bounds__(256, 4)
void k_attn(const unsigned short* __restrict__ Qg,   // [BH][S][64]
            const unsigned short* __restrict__ Kg,   // [BH][S][64]
            const unsigned short* __restrict__ Vtg,  // [BH][64][S]  (V^T)
            unsigned short* __restrict__ Og)         // [B][S][H*64] bf16
{
  __shared__ unsigned short Klds[64*64];   // [64 keys][64 dh], 16B-slot XOR swz
  __shared__ unsigned short Vlds[64*64];   // [64 dh][64 keys], 16B-slot XOR swz
  __shared__ float scL[128];
  const int tid = threadIdx.x;
  const int wid = tid >> 6, lane = tid & 63;
  const int ql = lane & 31, hi = lane >> 5;
  const int bh = blockIdx.x;
  const int qt = (int)gridDim.y - 1 - (int)blockIdx.y;  // longest first
  const int qbB = qt * 128;
  const int wq = qbB + wid * 32;

  const unsigned short* Qh  = Qg  + (size_t)bh*NS*NDH;
  const unsigned short* Kh  = Kg  + (size_t)bh*NS*NDH;
  const unsigned short* Vth = Vtg + (size_t)bh*NDH*NS;

  // Q fragments (B-operand): lane holds Q[q = wq+ql][dh = ds*16 + hi*8 + e]
  bf16x8 qf[4];
  #pragma unroll
  for (int ds=0; ds<4; ++ds)
    qf[ds] = *(const bf16x8*)(Qh + (size_t)(wq+ql)*NDH + ds*16 + hi*8);

  f32x16 acc0, acc1;
  #pragma unroll
  for (int r=0;r<16;++r) { acc0[r]=0.f; acc1[r]=0.f; }
  float lsum = 0.f;

  const int sr = tid >> 3, sc = tid & 7;        // sr 0..31, sc 0..7
  const int swz = (sc ^ (sr & 7)) * 8;          // constant per lane

  const int ntiles = 2*qt + 2;
  for (int kt = 0; kt < ntiles; ++kt) {
    const int kbase = kt << 6;
    #pragma unroll
    for (int c=0;c<2;c++)
      gload_lds16(Kh + (size_t)(kbase + c*32 + sr)*NDH + swz, &Klds[(c*256+tid)*8]);
    #pragma unroll
    for (int c=0;c<2;c++)
      gload_lds16(Vth + (size_t)(c*32 + sr)*NS + kbase + swz, &Vlds[(c*256+tid)*8]);
    __syncthreads();
    #pragma unroll
    for (int h32 = 0; h32 < 2; ++h32) {
      const int kb32 = kbase + h32*32;
      if (kb32 <= wq) {   // wave-uniform skip of fully-masked subtiles
        // S^T[key][q] = K · Q^T
        const int krow = h32*32 + ql;
        f32x16 st;
        #pragma unroll
        for (int r=0;r<16;++r) st[r] = 0.f;
        __builtin_amdgcn_s_setprio(1);
        #pragma unroll
        for (int ds=0; ds<4; ++ds) {
          bf16x8 kf = *(const bf16x8*)&Klds[krow*64 + (((ds*2+hi) ^ (krow&7))*8)];
          st = __builtin_amdgcn_mfma_f32_32x32x16_bf16(kf, qf[ds], st, 0,0,0);
        }
        __builtin_amdgcn_s_setprio(0);
        if (kb32 == wq) {  // diagonal subtile: causal mask
          #pragma unroll
          for (int r=0;r<16;++r) {
            const int koff = (r&3) + 8*(r>>2) + 4*hi;
            if (koff > ql) st[r] = -1e30f;
          }
        }
        // fixed-max softmax: P = 2^st (scores bounded, fp32 has headroom)
        float p[16]; float ls = 0.f;
        #pragma unroll
        for (int r=0;r<16;++r) { p[r] = __builtin_amdgcn_exp2f(st[r]); ls += p[r]; }
        lsum += ls;
        // pack P to PV A-fragments: cvt_pk + permlane32_swap (T12)
        unsigned w0 = cvtpk(p[0],p[1]),  w1 = cvtpk(p[2],p[3]);
        unsigned w2 = cvtpk(p[4],p[5]),  w3 = cvtpk(p[6],p[7]);
        plswap(w0, w2); plswap(w1, w3);
        unsigned z0 = cvtpk(p[8],p[9]),  z1 = cvtpk(p[10],p[11]);
        unsigned z2 = cvtpk(p[12],p[13]),z3 = cvtpk(p[14],p[15]);
        plswap(z0, z2); plswap(z1, z3);
        union { unsigned u[4]; bf16x8 v; } pk0, pk1;
        pk0.u[0]=w0; pk0.u[1]=w1; pk0.u[2]=w2; pk0.u[3]=w3;
        pk1.u[0]=z0; pk1.u[1]=z1; pk1.u[2]=z2; pk1.u[3]=z3;
        // PV: A = P (rows=queries), B = V^T-frag (cols=d)
        __builtin_amdgcn_s_setprio(1);
        #pragma unroll
        for (int nt=0; nt<2; ++nt) {
          const int drow = nt*32 + ql;
          #pragma unroll
          for (int ksl=0; ksl<2; ++ksl) {
            const int slot = h32*4 + ksl*2 + hi;
            bf16x8 vf = *(const bf16x8*)&Vlds[drow*64 + ((slot ^ (drow&7))*8)];
            f32x16 &a = nt ? acc1 : acc0;
            a = __builtin_amdgcn_mfma_f32_32x32x16_bf16(ksl ? pk1.v : pk0.v, vf, a, 0,0,0);
          }
        }
        __builtin_amdgcn_s_setprio(0);
      }
    }
    __syncthreads();
  }

  // epilogue: l = full row sum; broadcast 1/l via LDS (per-wave region)
  const float l = lsum + __shfl_xor(lsum, 32, 64);
  scL[wid*32 + ql] = 1.0f / l;
  const int b = bh >> 4, h = bh & 15;
  #pragma unroll
  for (int rq=0; rq<4; ++rq) {
    f32x4 lv = *(const f32x4*)&scL[wid*32 + rq*8 + 4*hi];
    #pragma unroll
    for (int j=0;j<4;j++) {
      const float inv = lv[j];
      const int s = wq + rq*8 + 4*hi + j;
      unsigned short* orow = Og + ((size_t)b*NS + s)*ND + h*NDH;
      orow[ql]      = f2bf(acc0[rq*4+j] * inv);
      orow[32 + ql] = f2bf(acc1[rq*4+j] * inv);
    }
  }
}

extern "C" void kernel_launch(void* const* d_in, const int* in_sizes, int n_in,
                              void* d_out, int out_size, void* d_ws, size_t ws_size,
                              hipStream_t stream) {
  (void)in_sizes; (void)n_in; (void)out_size; (void)ws_size;
  const float* x  = (const float*)d_in[0];
  const float* Wq = (const float*)d_in[1];
  const float* bq = (const float*)d_in[2];
  const float* Wk = (const float*)d_in[3];
  const float* bk = (const float*)d_in[4];
  const float* Wv = (const float*)d_in[5];
  const float* bv = (const float*)d_in[6];
  const float* Wo = (const float*)d_in[7];
  const float* bo = (const float*)d_in[8];

  char* ws = (char*)d_ws;
  unsigned short* xb  = (unsigned short*)(ws + 0);          // 16 MiB
  unsigned short* Wqb = (unsigned short*)(ws + 16777216);   // 2 MiB
  unsigned short* Wkb = (unsigned short*)(ws + 18874368);
  unsigned short* Wvb = (unsigned short*)(ws + 20971520);
  unsigned short* Wob = (unsigned short*)(ws + 23068672);
  unsigned short* Qb  = (unsigned short*)(ws + 25165824);   // 16 MiB each
  unsigned short* Kb  = (unsigned short*)(ws + 41943040);
  unsigned short* Vtb = (unsigned short*)(ws + 58720256);   // V^T [B,H,Dh,S]
  unsigned short* Ob  = (unsigned short*)(ws + 75497472);   // end: 92274688

  constexpr int CVT_BLOCKS = (NM*ND/8 + 4*ND*ND/8) / 256;   // 6144
  k_cvt_all<<<dim3(CVT_BLOCKS), dim3(256), 0, stream>>>(
      x, Wq, Wk, Wv, Wo, xb, Wqb, Wkb, Wvb, Wob);

  const float qscale = 0.125f * 1.4426950408889634f;  // 1/sqrt(64) * log2(e)
  k_gemm_qkv<<<dim3(24, NM/128), dim3(256), 0, stream>>>(
      xb, Wqb, Wkb, Wvb, bq, bk, bv, Qb, Kb, Vtb, qscale);

  k_attn<<<dim3(NB*NH, NS/128), dim3(256), 0, stream>>>(Qb, Kb, Vtb, Ob);

  k_gemm_o<<<dim3(ND/128, NM/128), dim3(256), 0, stream>>>(Ob, Wob, bo, (float*)d_out);
}

// Round 7
// 163.129 us; speedup vs baseline: 1.1859x; 1.1016x over previous
//
#include <hip/hip_runtime.h>
#include <hip/hip_bf16.h>
#include <stdint.h>

#define NB 4
#define NS 2048
#define ND 1024
#define NH 16
#define NDH 64
#define NM (NB*NS)   // 8192 rows

typedef __attribute__((ext_vector_type(8))) short bf16x8;
typedef __attribute__((ext_vector_type(4))) float f32x4;
typedef __attribute__((ext_vector_type(16))) float f32x16;
typedef __attribute__((ext_vector_type(8))) unsigned short u16x8;

static __device__ __forceinline__ unsigned short f2bf(float f) {
  union { float f; unsigned u; } v; v.f = f;
  return (unsigned short)((v.u + 0x7FFFu + ((v.u >> 16) & 1u)) >> 16);
}

static __device__ __forceinline__ void gload_lds16(const void* g, void* l) {
  __builtin_amdgcn_global_load_lds(
      (__attribute__((address_space(1))) unsigned int*)(uintptr_t)g,
      (__attribute__((address_space(3))) unsigned int*)(uintptr_t)(size_t)(l),
      16, 0, 0);
}

static __device__ __forceinline__ unsigned cvtpk(float lo, float hi) {
  unsigned r;
  asm("v_cvt_pk_bf16_f32 %0, %1, %2" : "=v"(r) : "v"(lo), "v"(hi));
  return r;
}
static __device__ __forceinline__ void plswap(unsigned &a, unsigned &b) {
  asm("v_permlane32_swap_b32 %0, %1" : "+v"(a), "+v"(b));
}

// ---------------- fused fp32 -> bf16 convert: x + 4 weights, one launch -----
__global__ void k_cvt_all(const float* __restrict__ x,
                          const float* __restrict__ s0, const float* __restrict__ s1,
                          const float* __restrict__ s2, const float* __restrict__ s3,
                          unsigned short* __restrict__ xd,
                          unsigned short* __restrict__ d0, unsigned short* __restrict__ d1,
                          unsigned short* __restrict__ d2, unsigned short* __restrict__ d3) {
  constexpr int NGX = NM*ND/8;     // x groups
  constexpr int NGW = ND*ND/8;     // groups per weight matrix
  int i = blockIdx.x * blockDim.x + threadIdx.x;   // grid sized exactly
  const float* src; unsigned short* dst; int j;
  if (i < NGX) { src = x; dst = xd; j = i; }
  else {
    const int k = i - NGX, m = k / NGW;
    j = k - m*NGW;
    src = m==0 ? s0 : (m==1 ? s1 : (m==2 ? s2 : s3));
    dst = m==0 ? d0 : (m==1 ? d1 : (m==2 ? d2 : d3));
  }
  const float4* s = (const float4*)src + (size_t)j * 2;
  float4 a = s[0], b = s[1];
  u16x8 o;
  o[0]=f2bf(a.x); o[1]=f2bf(a.y); o[2]=f2bf(a.z); o[3]=f2bf(a.w);
  o[4]=f2bf(b.x); o[5]=f2bf(b.y); o[6]=f2bf(b.z); o[7]=f2bf(b.w);
  *((u16x8*)dst + j) = o;
}

// ---------------- fused QKV GEMM: grid (24, 64), BK=64 + XOR swizzle --------
// C[i][j] = sum_k A[i][k]*W[j][k]; mat 0/1 -> bf16 [B,H,S,Dh]; mat 2 -> V^T
// LDS tiles [128 rows][64 k] bf16 (128 B rows). 16B slot s of row r holds
// global slot (s ^ (r&7)) -> fragment reads XOR the same way => 2-way max.
__global__ __launch_bounds__(256, 4)
void k_gemm_qkv(const unsigned short* __restrict__ A,
                const unsigned short* __restrict__ Wqp, const unsigned short* __restrict__ Wkp,
                const unsigned short* __restrict__ Wvp,
                const float* __restrict__ bqp, const float* __restrict__ bkp,
                const float* __restrict__ bvp,
                unsigned short* __restrict__ Qo, unsigned short* __restrict__ Ko,
                unsigned short* __restrict__ Vto, float qscale)
{
  constexpr int K = ND, BK = 64;
  __shared__ unsigned short Alds[128*BK];   // 16 KB
  __shared__ unsigned short Blds[128*BK];   // 16 KB
  const int bcf = blockIdx.x;
  const int mat = bcf >> 3, bc = bcf & 7;
  const unsigned short* W = mat==0 ? Wqp : (mat==1 ? Wkp : Wvp);
  const float* bias = mat==0 ? bqp : (mat==1 ? bkp : bvp);
  const float scale = mat==0 ? qscale : 1.0f;

  const int tid = threadIdx.x;
  const int wid = tid >> 6, lane = tid & 63;
  const int g = lane >> 4, lr = lane & 15;
  const int br = blockIdx.y;
  const int wr = (wid >> 1) << 6, wc = (wid & 1) << 6;

  f32x4 acc[4][4];
  #pragma unroll
  for (int m=0;m<4;m++)
    #pragma unroll
    for (int n=0;n<4;n++) acc[m][n] = f32x4{0.f,0.f,0.f,0.f};

  const unsigned short* Ab = A + (size_t)br*128*K;
  const unsigned short* Wb = W + (size_t)bc*128*K;

  // staging: linear LDS dest, inverse-swizzled global source (4+4 gloads)
  int srow[4], gcol[4];
  #pragma unroll
  for (int l=0;l<4;l++) {
    const int n = l*256 + tid;
    srow[l] = n >> 3;
    gcol[l] = ((n & 7) ^ (srow[l] & 7)) * 8;
  }

  for (int k0 = 0; k0 < K; k0 += BK) {
    #pragma unroll
    for (int l=0;l<4;l++)
      gload_lds16(Ab + (size_t)srow[l]*K + k0 + gcol[l], &Alds[(l*256+tid)*8]);
    #pragma unroll
    for (int l=0;l<4;l++)
      gload_lds16(Wb + (size_t)srow[l]*K + k0 + gcol[l], &Blds[(l*256+tid)*8]);
    __syncthreads();
    #pragma unroll
    for (int ks=0; ks<2; ++ks) {
      bf16x8 af[4], bfr[4];
      #pragma unroll
      for (int m=0;m<4;m++) {
        const int row = wr + m*16 + lr;
        af[m] = *(const bf16x8*)&Alds[row*BK + (((ks*4+g) ^ (row&7))*8)];
      }
      #pragma unroll
      for (int n=0;n<4;n++) {
        const int row = wc + n*16 + lr;
        bfr[n] = *(const bf16x8*)&Blds[row*BK + (((ks*4+g) ^ (row&7))*8)];
      }
      __builtin_amdgcn_s_setprio(1);
      #pragma unroll
      for (int m=0;m<4;m++)
        #pragma unroll
        for (int n=0;n<4;n++)
          acc[m][n] = __builtin_amdgcn_mfma_f32_16x16x32_bf16(af[m], bfr[n], acc[m][n], 0, 0, 0);
      __builtin_amdgcn_s_setprio(0);
    }
    __syncthreads();
  }

  #pragma unroll
  for (int m=0;m<4;m++) {
    const int rbase = br*128 + wr + m*16 + g*4;
    #pragma unroll
    for (int n=0;n<4;n++) {
      const int col = bc*128 + wc + n*16 + lr;
      const float bv = bias[col];
      #pragma unroll
      for (int j=0;j<4;j++) {
        const int row = rbase + j;
        const float val = (acc[m][n][j] + bv) * scale;
        const int b = row >> 11, s = row & (NS-1), h = col >> 6, dh = col & 63;
        if (mat == 2)
          Vto[(((size_t)b*NH + h)*NDH + dh)*NS + s] = f2bf(val);
        else
          (mat==0 ? Qo : Ko)[(((size_t)b*NH + h)*NS + s)*NDH + dh] = f2bf(val);
      }
    }
  }
}

// ---------------- O-projection GEMM (fp32 out), BK=64 + XOR swizzle ---------
__global__ __launch_bounds__(256, 4)
void k_gemm_o(const unsigned short* __restrict__ A,
              const unsigned short* __restrict__ W,
              const float* __restrict__ bias,
              float* __restrict__ outp)
{
  constexpr int K = ND, BK = 64;
  __shared__ unsigned short Alds[128*BK];
  __shared__ unsigned short Blds[128*BK];
  const int tid = threadIdx.x;
  const int wid = tid >> 6, lane = tid & 63;
  const int g = lane >> 4, lr = lane & 15;
  const int bc = blockIdx.x, br = blockIdx.y;
  const int wr = (wid >> 1) << 6, wc = (wid & 1) << 6;

  f32x4 acc[4][4];
  #pragma unroll
  for (int m=0;m<4;m++)
    #pragma unroll
    for (int n=0;n<4;n++) acc[m][n] = f32x4{0.f,0.f,0.f,0.f};

  const unsigned short* Ab = A + (size_t)br*128*K;
  const unsigned short* Wb = W + (size_t)bc*128*K;

  int srow[4], gcol[4];
  #pragma unroll
  for (int l=0;l<4;l++) {
    const int n = l*256 + tid;
    srow[l] = n >> 3;
    gcol[l] = ((n & 7) ^ (srow[l] & 7)) * 8;
  }

  for (int k0 = 0; k0 < K; k0 += BK) {
    #pragma unroll
    for (int l=0;l<4;l++)
      gload_lds16(Ab + (size_t)srow[l]*K + k0 + gcol[l], &Alds[(l*256+tid)*8]);
    #pragma unroll
    for (int l=0;l<4;l++)
      gload_lds16(Wb + (size_t)srow[l]*K + k0 + gcol[l], &Blds[(l*256+tid)*8]);
    __syncthreads();
    #pragma unroll
    for (int ks=0; ks<2; ++ks) {
      bf16x8 af[4], bfr[4];
      #pragma unroll
      for (int m=0;m<4;m++) {
        const int row = wr + m*16 + lr;
        af[m] = *(const bf16x8*)&Alds[row*BK + (((ks*4+g) ^ (row&7))*8)];
      }
      #pragma unroll
      for (int n=0;n<4;n++) {
        const int row = wc + n*16 + lr;
        bfr[n] = *(const bf16x8*)&Blds[row*BK + (((ks*4+g) ^ (row&7))*8)];
      }
      __builtin_amdgcn_s_setprio(1);
      #pragma unroll
      for (int m=0;m<4;m++)
        #pragma unroll
        for (int n=0;n<4;n++)
          acc[m][n] = __builtin_amdgcn_mfma_f32_16x16x32_bf16(af[m], bfr[n], acc[m][n], 0, 0, 0);
      __builtin_amdgcn_s_setprio(0);
    }
    __syncthreads();
  }

  #pragma unroll
  for (int m=0;m<4;m++) {
    const int rbase = br*128 + wr + m*16 + g*4;
    #pragma unroll
    for (int n=0;n<4;n++) {
      const int col = bc*128 + wc + n*16 + lr;
      const float bv = bias[col];
      #pragma unroll
      for (int j=0;j<4;j++)
        outp[(size_t)(rbase + j)*ND + col] = acc[m][n][j] + bv;
    }
  }
}

// ---------------- causal flash attention, swapped-QK^T 32x32 MFMA -----------
// grid (B*H, S/128); 4 waves x 32 q-rows; KV tiles of 64 keys, single-buffer.
// Q pre-scaled by 0.125*log2e. Fixed-max softmax: P = 2^st, normalize at end.
__global__ __launch_bounds__(256, 4)
void k_attn(const unsigned short* __restrict__ Qg,   // [BH][S][64]
            const unsigned short* __restrict__ Kg,   // [BH][S][64]
            const unsigned short* __restrict__ Vtg,  // [BH][64][S]  (V^T)
            unsigned short* __restrict__ Og)         // [B][S][H*64] bf16
{
  __shared__ unsigned short Klds[64*64];   // [64 keys][64 dh], 16B-slot XOR swz
  __shared__ unsigned short Vlds[64*64];   // [64 dh][64 keys], 16B-slot XOR swz
  __shared__ float scL[128];
  const int tid = threadIdx.x;
  const int wid = tid >> 6, lane = tid & 63;
  const int ql = lane & 31, hi = lane >> 5;
  const int bh = blockIdx.x;
  const int qt = (int)gridDim.y - 1 - (int)blockIdx.y;  // longest first
  const int qbB = qt * 128;
  const int wq = qbB + wid * 32;

  const unsigned short* Qh  = Qg  + (size_t)bh*NS*NDH;
  const unsigned short* Kh  = Kg  + (size_t)bh*NS*NDH;
  const unsigned short* Vth = Vtg + (size_t)bh*NDH*NS;

  // Q fragments (B-operand): lane holds Q[q = wq+ql][dh = ds*16 + hi*8 + e]
  bf16x8 qf[4];
  #pragma unroll
  for (int ds=0; ds<4; ++ds)
    qf[ds] = *(const bf16x8*)(Qh + (size_t)(wq+ql)*NDH + ds*16 + hi*8);

  f32x16 acc0, acc1;
  #pragma unroll
  for (int r=0;r<16;++r) { acc0[r]=0.f; acc1[r]=0.f; }
  float lsum = 0.f;

  const int sr = tid >> 3, sc = tid & 7;        // sr 0..31, sc 0..7
  const int swz = (sc ^ (sr & 7)) * 8;          // constant per lane

  const int ntiles = 2*qt + 2;
  for (int kt = 0; kt < ntiles; ++kt) {
    const int kbase = kt << 6;
    #pragma unroll
    for (int c=0;c<2;c++)
      gload_lds16(Kh + (size_t)(kbase + c*32 + sr)*NDH + swz, &Klds[(c*256+tid)*8]);
    #pragma unroll
    for (int c=0;c<2;c++)
      gload_lds16(Vth + (size_t)(c*32 + sr)*NS + kbase + swz, &Vlds[(c*256+tid)*8]);
    __syncthreads();
    #pragma unroll
    for (int h32 = 0; h32 < 2; ++h32) {
      const int kb32 = kbase + h32*32;
      if (kb32 <= wq) {   // wave-uniform skip of fully-masked subtiles
        // S^T[key][q] = K · Q^T
        const int krow = h32*32 + ql;
        f32x16 st;
        #pragma unroll
        for (int r=0;r<16;++r) st[r] = 0.f;
        __builtin_amdgcn_s_setprio(1);
        #pragma unroll
        for (int ds=0; ds<4; ++ds) {
          bf16x8 kf = *(const bf16x8*)&Klds[krow*64 + (((ds*2+hi) ^ (krow&7))*8)];
          st = __builtin_amdgcn_mfma_f32_32x32x16_bf16(kf, qf[ds], st, 0,0,0);
        }
        __builtin_amdgcn_s_setprio(0);
        if (kb32 == wq) {  // diagonal subtile: causal mask
          #pragma unroll
          for (int r=0;r<16;++r) {
            const int koff = (r&3) + 8*(r>>2) + 4*hi;
            if (koff > ql) st[r] = -1e30f;
          }
        }
        // fixed-max softmax: P = 2^st (scores bounded, fp32 has headroom)
        float p[16]; float ls = 0.f;
        #pragma unroll
        for (int r=0;r<16;++r) { p[r] = __builtin_amdgcn_exp2f(st[r]); ls += p[r]; }
        lsum += ls;
        // pack P to PV A-fragments: cvt_pk + permlane32_swap (T12)
        unsigned w0 = cvtpk(p[0],p[1]),  w1 = cvtpk(p[2],p[3]);
        unsigned w2 = cvtpk(p[4],p[5]),  w3 = cvtpk(p[6],p[7]);
        plswap(w0, w2); plswap(w1, w3);
        unsigned z0 = cvtpk(p[8],p[9]),  z1 = cvtpk(p[10],p[11]);
        unsigned z2 = cvtpk(p[12],p[13]),z3 = cvtpk(p[14],p[15]);
        plswap(z0, z2); plswap(z1, z3);
        union { unsigned u[4]; bf16x8 v; } pk0, pk1;
        pk0.u[0]=w0; pk0.u[1]=w1; pk0.u[2]=w2; pk0.u[3]=w3;
        pk1.u[0]=z0; pk1.u[1]=z1; pk1.u[2]=z2; pk1.u[3]=z3;
        // PV: A = P (rows=queries), B = V^T-frag (cols=d)
        __builtin_amdgcn_s_setprio(1);
        #pragma unroll
        for (int nt=0; nt<2; ++nt) {
          const int drow = nt*32 + ql;
          #pragma unroll
          for (int ksl=0; ksl<2; ++ksl) {
            const int slot = h32*4 + ksl*2 + hi;
            bf16x8 vf = *(const bf16x8*)&Vlds[drow*64 + ((slot ^ (drow&7))*8)];
            f32x16 &a = nt ? acc1 : acc0;
            a = __builtin_amdgcn_mfma_f32_32x32x16_bf16(ksl ? pk1.v : pk0.v, vf, a, 0,0,0);
          }
        }
        __builtin_amdgcn_s_setprio(0);
      }
    }
    __syncthreads();
  }

  // epilogue: l = full row sum; broadcast 1/l via LDS (per-wave region)
  const float l = lsum + __shfl_xor(lsum, 32, 64);
  scL[wid*32 + ql] = 1.0f / l;
  const int b = bh >> 4, h = bh & 15;
  #pragma unroll
  for (int rq=0; rq<4; ++rq) {
    f32x4 lv = *(const f32x4*)&scL[wid*32 + rq*8 + 4*hi];
    #pragma unroll
    for (int j=0;j<4;j++) {
      const float inv = lv[j];
      const int s = wq + rq*8 + 4*hi + j;
      unsigned short* orow = Og + ((size_t)b*NS + s)*ND + h*NDH;
      orow[ql]      = f2bf(acc0[rq*4+j] * inv);
      orow[32 + ql] = f2bf(acc1[rq*4+j] * inv);
    }
  }
}

extern "C" void kernel_launch(void* const* d_in, const int* in_sizes, int n_in,
                              void* d_out, int out_size, void* d_ws, size_t ws_size,
                              hipStream_t stream) {
  (void)in_sizes; (void)n_in; (void)out_size; (void)ws_size;
  const float* x  = (const float*)d_in[0];
  const float* Wq = (const float*)d_in[1];
  const float* bq = (const float*)d_in[2];
  const float* Wk = (const float*)d_in[3];
  const float* bk = (const float*)d_in[4];
  const float* Wv = (const float*)d_in[5];
  const float* bv = (const float*)d_in[6];
  const float* Wo = (const float*)d_in[7];
  const float* bo = (const float*)d_in[8];

  char* ws = (char*)d_ws;
  unsigned short* xb  = (unsigned short*)(ws + 0);          // 16 MiB
  unsigned short* Wqb = (unsigned short*)(ws + 16777216);   // 2 MiB
  unsigned short* Wkb = (unsigned short*)(ws + 18874368);
  unsigned short* Wvb = (unsigned short*)(ws + 20971520);
  unsigned short* Wob = (unsigned short*)(ws + 23068672);
  unsigned short* Qb  = (unsigned short*)(ws + 25165824);   // 16 MiB each
  unsigned short* Kb  = (unsigned short*)(ws + 41943040);
  unsigned short* Vtb = (unsigned short*)(ws + 58720256);   // V^T [B,H,Dh,S]
  unsigned short* Ob  = (unsigned short*)(ws + 75497472);   // end: 92274688

  constexpr int CVT_BLOCKS = (NM*ND/8 + 4*ND*ND/8) / 256;   // 6144
  k_cvt_all<<<dim3(CVT_BLOCKS), dim3(256), 0, stream>>>(
      x, Wq, Wk, Wv, Wo, xb, Wqb, Wkb, Wvb, Wob);

  const float qscale = 0.125f * 1.4426950408889634f;  // 1/sqrt(64) * log2(e)
  k_gemm_qkv<<<dim3(24, NM/128), dim3(256), 0, stream>>>(
      xb, Wqb, Wkb, Wvb, bq, bk, bv, Qb, Kb, Vtb, qscale);

  k_attn<<<dim3(NB*NH, NS/128), dim3(256), 0, stream>>>(Qb, Kb, Vtb, Ob);

  k_gemm_o<<<dim3(ND/128, NM/128), dim3(256), 0, stream>>>(Ob, Wob, bo, (float*)d_out);
}